// Round 7
// baseline (51.706 us; speedup 1.0000x reference)
//
#include <hip/hip_runtime.h>
#include <math.h>

#define D 256
#define COPY_FLOATS 1028   // 4 groups * 256 sums + 4 counts
#define NCOPIES_MAX 32
#define GRID_BLOCKS 1024   // 4096 waves -> exactly one 64-row chunk per wave

// R3-validated main structure (64-row chunks, 4-deep MLP, spread atomics)
// + last-block-done finalize tail (R4 mechanism, minus R4's confounders:
// no 8-deep body, no __launch_bounds__ min-occupancy clamp).
__global__ __launch_bounds__(256) void rank_loss_fused(
    const float* __restrict__ F, const float* __restrict__ T,
    float* __restrict__ ws, unsigned* __restrict__ counter,
    float* __restrict__ out, int nRows, int ncopies)
{
    __shared__ float lsum[4][4][D];   // [wave][group][col]
    __shared__ float lcnt[4][4];      // [wave][group]

    const int tid  = threadIdx.x;
    const int lane = tid & 63;
    const int wav  = tid >> 6;
    const long long waveId = (long long)blockIdx.x * 4 + wav;
    const long long nWaves = (long long)gridDim.x * 4;

    float4 a0 = {0.f,0.f,0.f,0.f}, a1 = a0, a2 = a0, a3 = a0;
    float c0 = 0.f, c1 = 0.f, c2 = 0.f, c3 = 0.f;

    for (long long base = waveId * 64; base < (long long)nRows;
         base += nWaves * 64) {
        const long long r = base + lane;
        const float t = (r < (long long)nRows) ? T[r] : 2.0f;  // sentinel

        // 64-bit ballots: bit i = membership of row base+i (wave-uniform)
        const unsigned long long m0 = __ballot(t <= 0.1f);
        const unsigned long long m1 = __ballot(t > 0.3f && t <= 0.4f);
        const unsigned long long m2 = __ballot(t > 0.6f && t <= 0.7f);
        const unsigned long long m3 = __ballot(t > 0.8f && t <= 1.1f);

        c0 += (float)__popcll(m0);
        c1 += (float)__popcll(m1);
        c2 += (float)__popcll(m2);
        c3 += (float)__popcll(m3);

        const float* Fb = F + (size_t)base * D + (size_t)lane * 4;
        unsigned long long mAll = m0 | m1 | m2 | m3;

        auto addRow = [&](int jj, const float4& v) {
            // jj and mask bits are wave-uniform -> scalar branch, no divergence
            if ((m0 >> jj) & 1ull) {
                a0.x += v.x; a0.y += v.y; a0.z += v.z; a0.w += v.w;
            } else if ((m1 >> jj) & 1ull) {
                a1.x += v.x; a1.y += v.y; a1.z += v.z; a1.w += v.w;
            } else if ((m2 >> jj) & 1ull) {
                a2.x += v.x; a2.y += v.y; a2.z += v.z; a2.w += v.w;
            } else {
                a3.x += v.x; a3.y += v.y; a3.z += v.z; a3.w += v.w;
            }
        };

        // 4-wide body: 4 independent 1KB row loads in flight per wave
        // (validated R3; 8-wide regressed, R5)
        while (__popcll(mAll) >= 4) {
            const int j0 = __ffsll(mAll) - 1; mAll &= mAll - 1;
            const int j1 = __ffsll(mAll) - 1; mAll &= mAll - 1;
            const int j2 = __ffsll(mAll) - 1; mAll &= mAll - 1;
            const int j3 = __ffsll(mAll) - 1; mAll &= mAll - 1;
            const float4 v0 = *reinterpret_cast<const float4*>(Fb + (size_t)j0 * D);
            const float4 v1 = *reinterpret_cast<const float4*>(Fb + (size_t)j1 * D);
            const float4 v2 = *reinterpret_cast<const float4*>(Fb + (size_t)j2 * D);
            const float4 v3 = *reinterpret_cast<const float4*>(Fb + (size_t)j3 * D);
            addRow(j0, v0); addRow(j1, v1); addRow(j2, v2); addRow(j3, v3);
        }
        while (mAll) {
            const int j0 = __ffsll(mAll) - 1; mAll &= mAll - 1;
            const float4 v0 = *reinterpret_cast<const float4*>(Fb + (size_t)j0 * D);
            addRow(j0, v0);
        }
    }

    // per-wave partials -> LDS
    *reinterpret_cast<float4*>(&lsum[wav][0][lane * 4]) = a0;
    *reinterpret_cast<float4*>(&lsum[wav][1][lane * 4]) = a1;
    *reinterpret_cast<float4*>(&lsum[wav][2][lane * 4]) = a2;
    *reinterpret_cast<float4*>(&lsum[wav][3][lane * 4]) = a3;
    if (lane == 0) {
        lcnt[wav][0] = c0; lcnt[wav][1] = c1; lcnt[wav][2] = c2; lcnt[wav][3] = c3;
    }
    __syncthreads();

    // block-level reduce across the 4 waves -> spread atomics (device scope)
    float* dst = ws + (size_t)(blockIdx.x % ncopies) * COPY_FLOATS;
#pragma unroll
    for (int g = 0; g < 4; ++g) {
        const float s = lsum[0][g][tid] + lsum[1][g][tid]
                      + lsum[2][g][tid] + lsum[3][g][tid];
        atomicAdd(dst + g * D + tid, s);
    }
    if (tid < 4) {
        const float c = lcnt[0][tid] + lcnt[1][tid] + lcnt[2][tid] + lcnt[3][tid];
        atomicAdd(dst + 4 * D + tid, c);
    }

    // ---- release: wait for this thread's atomics to be performed at the
    // coherence point. Cheap (no cache writeback/invalidate, unlike the
    // per-thread __threadfence that sank R2).
    asm volatile("s_waitcnt vmcnt(0)" ::: "memory");
    __syncthreads();

    __shared__ int isLast;
    if (tid == 0) {
        const unsigned old = atomicAdd(counter, 1u);
        isLast = (old == (unsigned)(gridDim.x - 1)) ? 1 : 0;
    }
    __syncthreads();
    if (!isLast) return;

    // ---- acquire (single last block only) then finalize
    __threadfence();

    float s[4] = {0.f,0.f,0.f,0.f};
    float cc[4] = {0.f,0.f,0.f,0.f};
#pragma unroll 4
    for (int cp = 0; cp < ncopies; ++cp) {
        const float* w = ws + (size_t)cp * COPY_FLOATS;
#pragma unroll
        for (int g = 0; g < 4; ++g) {
            s[g]  += w[g * D + tid];
            cc[g] += w[4 * D + g];
        }
    }

    float m[4];
#pragma unroll
    for (int g = 0; g < 4; ++g)
        m[g] = (cc[g] > 0.f) ? s[g] / fmaxf(cc[g], 1.f) : 0.f;

    float p[6];
    p[0] = (m[0]-m[1]) * (m[0]-m[1]);   // d12
    p[1] = (m[0]-m[2]) * (m[0]-m[2]);   // d13
    p[2] = (m[0]-m[3]) * (m[0]-m[3]);   // d14
    p[3] = (m[1]-m[2]) * (m[1]-m[2]);   // d23
    p[4] = (m[1]-m[3]) * (m[1]-m[3]);   // d24
    p[5] = (m[2]-m[3]) * (m[2]-m[3]);   // d34

    __shared__ float red[6][4];
#pragma unroll
    for (int k = 0; k < 6; ++k) {
        float v = p[k];
#pragma unroll
        for (int off = 32; off >= 1; off >>= 1)
            v += __shfl_down(v, off, 64);
        if (lane == 0) red[k][wav] = v;
    }
    __syncthreads();

    if (tid == 0) {
        float d[6];
#pragma unroll
        for (int k = 0; k < 6; ++k)
            d[k] = sqrtf(red[k][0] + red[k][1] + red[k][2] + red[k][3]);
        const float d12 = d[0], d13 = d[1], d14 = d[2];
        const float d23 = d[3], d24 = d[4], d34 = d[5];
        const float M = 0.75f;
        const float loss =
              fmaxf(d12 - d13 + M, 0.f)       + fmaxf(d12 - d14 + 2.f * M, 0.f)
            + fmaxf(d23 - d24 + M, 0.f)       + fmaxf(d23 - d14 + 2.f * M, 0.f)
            + fmaxf(d34 - d24 + M, 0.f)       + fmaxf(d34 - d14 + 2.f * M, 0.f);
        out[0] = loss;
    }
}

extern "C" void kernel_launch(void* const* d_in, const int* in_sizes, int n_in,
                              void* d_out, int out_size, void* d_ws, size_t ws_size,
                              hipStream_t stream) {
    const float* F = (const float*)d_in[0];   // feature_results [N, 256] fp32
    const float* T = (const float*)d_in[1];   // target_var [N] fp32
    float* out = (float*)d_out;
    const int nRows = in_sizes[1];

    // layout: [ncopies * COPY_FLOATS floats][counter u32 (in trailing 64B)]
    int ncopies = (int)((ws_size - 64) / (COPY_FLOATS * sizeof(float)));
    if (ncopies > NCOPIES_MAX) ncopies = NCOPIES_MAX;
    if (ncopies < 1) ncopies = 1;
    const size_t copies_bytes = (size_t)ncopies * COPY_FLOATS * sizeof(float);

    float* ws = (float*)d_ws;
    unsigned* counter = (unsigned*)((char*)d_ws + copies_bytes);

    // atomics accumulate into ws; counter must start at 0 -> re-zero per launch
    hipMemsetAsync(d_ws, 0, copies_bytes + 64, stream);

    rank_loss_fused<<<GRID_BLOCKS, 256, 0, stream>>>(
        F, T, ws, counter, out, nRows, ncopies);
}

// Round 8
// 42.567 us; speedup vs baseline: 1.2147x; 1.2147x over previous
//
#include <hip/hip_runtime.h>
#include <math.h>

#define D 256
#define COPY_FLOATS 1028   // 4 groups * 256 sums + 4 counts
#define NCOPIES_MAX 8      // R8: 32 -> 8 (4x smaller memset + finalize read)
#define GRID_BLOCKS 1024   // 4096 waves -> exactly one 64-row chunk per wave

// Main kernel (R3-validated): each wave owns one contiguous 64-row chunk.
// Coalesced 64-lane T load -> 64-bit ballots -> member mask in SGPRs
// (wave-uniform). Member rows popped 4 at a time: 4 independent
// global_load_dwordx4 in flight per wave before any consume.
// (8-deep regressed: R5, likely spill. Fusions regressed: R2/R4/R7.)
__global__ __launch_bounds__(256) void group_partial(
    const float* __restrict__ F, const float* __restrict__ T,
    float* __restrict__ ws, int nRows, int ncopies)
{
    __shared__ float lsum[4][4][D];   // [wave][group][col]
    __shared__ float lcnt[4][4];      // [wave][group]

    const int tid  = threadIdx.x;
    const int lane = tid & 63;
    const int wav  = tid >> 6;
    const long long waveId = (long long)blockIdx.x * 4 + wav;
    const long long nWaves = (long long)gridDim.x * 4;

    float4 a0 = {0.f,0.f,0.f,0.f}, a1 = a0, a2 = a0, a3 = a0;
    float c0 = 0.f, c1 = 0.f, c2 = 0.f, c3 = 0.f;

    for (long long base = waveId * 64; base < (long long)nRows;
         base += nWaves * 64) {
        const long long r = base + lane;
        const float t = (r < (long long)nRows) ? T[r] : 2.0f;  // sentinel

        // 64-bit ballots: bit i = membership of row base+i (wave-uniform)
        const unsigned long long m0 = __ballot(t <= 0.1f);
        const unsigned long long m1 = __ballot(t > 0.3f && t <= 0.4f);
        const unsigned long long m2 = __ballot(t > 0.6f && t <= 0.7f);
        const unsigned long long m3 = __ballot(t > 0.8f && t <= 1.1f);

        c0 += (float)__popcll(m0);
        c1 += (float)__popcll(m1);
        c2 += (float)__popcll(m2);
        c3 += (float)__popcll(m3);

        const float* Fb = F + (size_t)base * D + (size_t)lane * 4;
        unsigned long long mAll = m0 | m1 | m2 | m3;

        auto addRow = [&](int jj, const float4& v) {
            // jj and mask bits are wave-uniform -> scalar branch, no divergence
            if ((m0 >> jj) & 1ull) {
                a0.x += v.x; a0.y += v.y; a0.z += v.z; a0.w += v.w;
            } else if ((m1 >> jj) & 1ull) {
                a1.x += v.x; a1.y += v.y; a1.z += v.z; a1.w += v.w;
            } else if ((m2 >> jj) & 1ull) {
                a2.x += v.x; a2.y += v.y; a2.z += v.z; a2.w += v.w;
            } else {
                a3.x += v.x; a3.y += v.y; a3.z += v.z; a3.w += v.w;
            }
        };

        // 4-wide body: 4 independent 1KB row loads in flight per wave
        while (__popcll(mAll) >= 4) {
            const int j0 = __ffsll(mAll) - 1; mAll &= mAll - 1;
            const int j1 = __ffsll(mAll) - 1; mAll &= mAll - 1;
            const int j2 = __ffsll(mAll) - 1; mAll &= mAll - 1;
            const int j3 = __ffsll(mAll) - 1; mAll &= mAll - 1;
            const float4 v0 = *reinterpret_cast<const float4*>(Fb + (size_t)j0 * D);
            const float4 v1 = *reinterpret_cast<const float4*>(Fb + (size_t)j1 * D);
            const float4 v2 = *reinterpret_cast<const float4*>(Fb + (size_t)j2 * D);
            const float4 v3 = *reinterpret_cast<const float4*>(Fb + (size_t)j3 * D);
            addRow(j0, v0); addRow(j1, v1); addRow(j2, v2); addRow(j3, v3);
        }
        while (mAll) {
            const int j0 = __ffsll(mAll) - 1; mAll &= mAll - 1;
            const float4 v0 = *reinterpret_cast<const float4*>(Fb + (size_t)j0 * D);
            addRow(j0, v0);
        }
    }

    // per-wave partials -> LDS
    *reinterpret_cast<float4*>(&lsum[wav][0][lane * 4]) = a0;
    *reinterpret_cast<float4*>(&lsum[wav][1][lane * 4]) = a1;
    *reinterpret_cast<float4*>(&lsum[wav][2][lane * 4]) = a2;
    *reinterpret_cast<float4*>(&lsum[wav][3][lane * 4]) = a3;
    if (lane == 0) {
        lcnt[wav][0] = c0; lcnt[wav][1] = c1; lcnt[wav][2] = c2; lcnt[wav][3] = c3;
    }
    __syncthreads();

    // block-level reduce across the 4 waves, one atomic per element,
    // spread across ncopies partial copies (128-deep chains at 1024 blocks /
    // 8 copies -- amortized over the grid's natural drain)
    float* dst = ws + (size_t)(blockIdx.x % ncopies) * COPY_FLOATS;
#pragma unroll
    for (int g = 0; g < 4; ++g) {
        const float s = lsum[0][g][tid] + lsum[1][g][tid]
                      + lsum[2][g][tid] + lsum[3][g][tid];
        atomicAdd(dst + g * D + tid, s);
    }
    if (tid < 4) {
        const float c = lcnt[0][tid] + lcnt[1][tid] + lcnt[2][tid] + lcnt[3][tid];
        atomicAdd(dst + 4 * D + tid, c);
    }
}

__global__ __launch_bounds__(256) void finalize(
    const float* __restrict__ ws, int ncopies, float* __restrict__ out)
{
    const int tid  = threadIdx.x;
    const int lane = tid & 63;
    const int wav  = tid >> 6;

    // 8 copies x 4 groups = 32 independent 4B loads per thread (one L2
    // latency round-trip when fully unrolled, vs R3's 32-iteration loop)
    float s[4] = {0.f,0.f,0.f,0.f};
    float c[4] = {0.f,0.f,0.f,0.f};
#pragma unroll 8
    for (int cp = 0; cp < ncopies; ++cp) {
        const float* w = ws + (size_t)cp * COPY_FLOATS;
#pragma unroll
        for (int g = 0; g < 4; ++g) {
            s[g] += w[g * D + tid];
            c[g] += w[4 * D + g];
        }
    }

    float m[4];
#pragma unroll
    for (int g = 0; g < 4; ++g)
        m[g] = (c[g] > 0.f) ? s[g] / fmaxf(c[g], 1.f) : 0.f;

    float p[6];
    p[0] = (m[0]-m[1]) * (m[0]-m[1]);   // d12
    p[1] = (m[0]-m[2]) * (m[0]-m[2]);   // d13
    p[2] = (m[0]-m[3]) * (m[0]-m[3]);   // d14
    p[3] = (m[1]-m[2]) * (m[1]-m[2]);   // d23
    p[4] = (m[1]-m[3]) * (m[1]-m[3]);   // d24
    p[5] = (m[2]-m[3]) * (m[2]-m[3]);   // d34

    __shared__ float red[6][4];
#pragma unroll
    for (int k = 0; k < 6; ++k) {
        float v = p[k];
#pragma unroll
        for (int off = 32; off >= 1; off >>= 1)
            v += __shfl_down(v, off, 64);
        if (lane == 0) red[k][wav] = v;
    }
    __syncthreads();

    if (tid == 0) {
        float d[6];
#pragma unroll
        for (int k = 0; k < 6; ++k)
            d[k] = sqrtf(red[k][0] + red[k][1] + red[k][2] + red[k][3]);
        const float d12 = d[0], d13 = d[1], d14 = d[2];
        const float d23 = d[3], d24 = d[4], d34 = d[5];
        const float M = 0.75f;
        const float loss =
              fmaxf(d12 - d13 + M, 0.f)       + fmaxf(d12 - d14 + 2.f * M, 0.f)
            + fmaxf(d23 - d24 + M, 0.f)       + fmaxf(d23 - d14 + 2.f * M, 0.f)
            + fmaxf(d34 - d24 + M, 0.f)       + fmaxf(d34 - d14 + 2.f * M, 0.f);
        out[0] = loss;
    }
}

extern "C" void kernel_launch(void* const* d_in, const int* in_sizes, int n_in,
                              void* d_out, int out_size, void* d_ws, size_t ws_size,
                              hipStream_t stream) {
    const float* F = (const float*)d_in[0];   // feature_results [N, 256] fp32
    const float* T = (const float*)d_in[1];   // target_var [N] fp32
    float* out = (float*)d_out;
    const int nRows = in_sizes[1];

    int ncopies = (int)(ws_size / (COPY_FLOATS * sizeof(float)));
    if (ncopies > NCOPIES_MAX) ncopies = NCOPIES_MAX;
    if (ncopies < 1) ncopies = 1;

    // atomics accumulate into ws -> must re-zero every launch (capture-safe);
    // only 33 KB now
    hipMemsetAsync(d_ws, 0, (size_t)ncopies * COPY_FLOATS * sizeof(float), stream);

    group_partial<<<GRID_BLOCKS, 256, 0, stream>>>(F, T, (float*)d_ws, nRows, ncopies);
    finalize<<<1, 256, 0, stream>>>((const float*)d_ws, ncopies, out);
}

// Round 9
// 42.498 us; speedup vs baseline: 1.2167x; 1.0016x over previous
//
#include <hip/hip_runtime.h>
#include <math.h>

#define D 256
#define COPY_FLOATS 1028   // 4 groups * 256 sums + 4 counts
#define NCOPIES_MAX 8      // R8-validated (4x smaller memset + finalize read)
#define GRID_BLOCKS 512    // x 512 thr = 4096 waves -> one 64-row chunk each
#define WAVES_PB 8

// Main kernel (R3/R8-validated memory pattern): each wave owns one contiguous
// 64-row chunk. Coalesced 64-lane T load -> 64-bit ballots -> member mask in
// SGPRs (wave-uniform). Member rows popped 4 at a time: 4 independent
// global_load_dwordx4 in flight per wave before any consume.
// R9 change: 512 blocks x 8 waves (was 1024 x 4) -- same 4096 waves, half the
// atomic sets and block tails. (8-deep regressed: R5. Fusions: R2/R4/R7.)
__global__ __launch_bounds__(512) void group_partial(
    const float* __restrict__ F, const float* __restrict__ T,
    float* __restrict__ ws, int nRows, int ncopies)
{
    __shared__ float lsum[WAVES_PB][4][D];   // [wave][group][col] = 32 KB
    __shared__ float lcnt[WAVES_PB][4];      // [wave][group]

    const int tid  = threadIdx.x;
    const int lane = tid & 63;
    const int wav  = tid >> 6;               // 0..7
    const long long waveId = (long long)blockIdx.x * WAVES_PB + wav;
    const long long nWaves = (long long)gridDim.x * WAVES_PB;

    float4 a0 = {0.f,0.f,0.f,0.f}, a1 = a0, a2 = a0, a3 = a0;
    float c0 = 0.f, c1 = 0.f, c2 = 0.f, c3 = 0.f;

    for (long long base = waveId * 64; base < (long long)nRows;
         base += nWaves * 64) {
        const long long r = base + lane;
        const float t = (r < (long long)nRows) ? T[r] : 2.0f;  // sentinel

        // 64-bit ballots: bit i = membership of row base+i (wave-uniform)
        const unsigned long long m0 = __ballot(t <= 0.1f);
        const unsigned long long m1 = __ballot(t > 0.3f && t <= 0.4f);
        const unsigned long long m2 = __ballot(t > 0.6f && t <= 0.7f);
        const unsigned long long m3 = __ballot(t > 0.8f && t <= 1.1f);

        c0 += (float)__popcll(m0);
        c1 += (float)__popcll(m1);
        c2 += (float)__popcll(m2);
        c3 += (float)__popcll(m3);

        const float* Fb = F + (size_t)base * D + (size_t)lane * 4;
        unsigned long long mAll = m0 | m1 | m2 | m3;

        auto addRow = [&](int jj, const float4& v) {
            // jj and mask bits are wave-uniform -> scalar branch, no divergence
            if ((m0 >> jj) & 1ull) {
                a0.x += v.x; a0.y += v.y; a0.z += v.z; a0.w += v.w;
            } else if ((m1 >> jj) & 1ull) {
                a1.x += v.x; a1.y += v.y; a1.z += v.z; a1.w += v.w;
            } else if ((m2 >> jj) & 1ull) {
                a2.x += v.x; a2.y += v.y; a2.z += v.z; a2.w += v.w;
            } else {
                a3.x += v.x; a3.y += v.y; a3.z += v.z; a3.w += v.w;
            }
        };

        // 4-wide body: 4 independent 1KB row loads in flight per wave
        while (__popcll(mAll) >= 4) {
            const int j0 = __ffsll(mAll) - 1; mAll &= mAll - 1;
            const int j1 = __ffsll(mAll) - 1; mAll &= mAll - 1;
            const int j2 = __ffsll(mAll) - 1; mAll &= mAll - 1;
            const int j3 = __ffsll(mAll) - 1; mAll &= mAll - 1;
            const float4 v0 = *reinterpret_cast<const float4*>(Fb + (size_t)j0 * D);
            const float4 v1 = *reinterpret_cast<const float4*>(Fb + (size_t)j1 * D);
            const float4 v2 = *reinterpret_cast<const float4*>(Fb + (size_t)j2 * D);
            const float4 v3 = *reinterpret_cast<const float4*>(Fb + (size_t)j3 * D);
            addRow(j0, v0); addRow(j1, v1); addRow(j2, v2); addRow(j3, v3);
        }
        while (mAll) {
            const int j0 = __ffsll(mAll) - 1; mAll &= mAll - 1;
            const float4 v0 = *reinterpret_cast<const float4*>(Fb + (size_t)j0 * D);
            addRow(j0, v0);
        }
    }

    // per-wave partials -> LDS
    *reinterpret_cast<float4*>(&lsum[wav][0][lane * 4]) = a0;
    *reinterpret_cast<float4*>(&lsum[wav][1][lane * 4]) = a1;
    *reinterpret_cast<float4*>(&lsum[wav][2][lane * 4]) = a2;
    *reinterpret_cast<float4*>(&lsum[wav][3][lane * 4]) = a3;
    if (lane == 0) {
        lcnt[wav][0] = c0; lcnt[wav][1] = c1; lcnt[wav][2] = c2; lcnt[wav][3] = c3;
    }
    __syncthreads();

    // block reduce across 8 waves: threads 0-255 handle groups 0,1;
    // threads 256-511 handle groups 2,3 -> 2 atomics per thread
    float* dst = ws + (size_t)(blockIdx.x % ncopies) * COPY_FLOATS;
    const int col  = tid & 255;
    const int gsel = (tid >> 8) * 2;   // 0 or 2
#pragma unroll
    for (int gg = 0; gg < 2; ++gg) {
        const int g = gsel + gg;
        float s = 0.f;
#pragma unroll
        for (int w = 0; w < WAVES_PB; ++w) s += lsum[w][g][col];
        atomicAdd(dst + g * D + col, s);
    }
    if (tid < 4) {
        float c = 0.f;
#pragma unroll
        for (int w = 0; w < WAVES_PB; ++w) c += lcnt[w][tid];
        atomicAdd(dst + 4 * D + tid, c);
    }
}

__global__ __launch_bounds__(256) void finalize(
    const float* __restrict__ ws, int ncopies, float* __restrict__ out)
{
    const int tid  = threadIdx.x;
    const int lane = tid & 63;
    const int wav  = tid >> 6;

    // 8 copies x 4 groups = 32 independent 4B loads per thread, fully unrolled
    float s[4] = {0.f,0.f,0.f,0.f};
    float c[4] = {0.f,0.f,0.f,0.f};
#pragma unroll 8
    for (int cp = 0; cp < ncopies; ++cp) {
        const float* w = ws + (size_t)cp * COPY_FLOATS;
#pragma unroll
        for (int g = 0; g < 4; ++g) {
            s[g] += w[g * D + tid];
            c[g] += w[4 * D + g];
        }
    }

    float m[4];
#pragma unroll
    for (int g = 0; g < 4; ++g)
        m[g] = (c[g] > 0.f) ? s[g] / fmaxf(c[g], 1.f) : 0.f;

    float p[6];
    p[0] = (m[0]-m[1]) * (m[0]-m[1]);   // d12
    p[1] = (m[0]-m[2]) * (m[0]-m[2]);   // d13
    p[2] = (m[0]-m[3]) * (m[0]-m[3]);   // d14
    p[3] = (m[1]-m[2]) * (m[1]-m[2]);   // d23
    p[4] = (m[1]-m[3]) * (m[1]-m[3]);   // d24
    p[5] = (m[2]-m[3]) * (m[2]-m[3]);   // d34

    __shared__ float red[6][4];
#pragma unroll
    for (int k = 0; k < 6; ++k) {
        float v = p[k];
#pragma unroll
        for (int off = 32; off >= 1; off >>= 1)
            v += __shfl_down(v, off, 64);
        if (lane == 0) red[k][wav] = v;
    }
    __syncthreads();

    if (tid == 0) {
        float d[6];
#pragma unroll
        for (int k = 0; k < 6; ++k)
            d[k] = sqrtf(red[k][0] + red[k][1] + red[k][2] + red[k][3]);
        const float d12 = d[0], d13 = d[1], d14 = d[2];
        const float d23 = d[3], d24 = d[4], d34 = d[5];
        const float M = 0.75f;
        const float loss =
              fmaxf(d12 - d13 + M, 0.f)       + fmaxf(d12 - d14 + 2.f * M, 0.f)
            + fmaxf(d23 - d24 + M, 0.f)       + fmaxf(d23 - d14 + 2.f * M, 0.f)
            + fmaxf(d34 - d24 + M, 0.f)       + fmaxf(d34 - d14 + 2.f * M, 0.f);
        out[0] = loss;
    }
}

extern "C" void kernel_launch(void* const* d_in, const int* in_sizes, int n_in,
                              void* d_out, int out_size, void* d_ws, size_t ws_size,
                              hipStream_t stream) {
    const float* F = (const float*)d_in[0];   // feature_results [N, 256] fp32
    const float* T = (const float*)d_in[1];   // target_var [N] fp32
    float* out = (float*)d_out;
    const int nRows = in_sizes[1];

    int ncopies = (int)(ws_size / (COPY_FLOATS * sizeof(float)));
    if (ncopies > NCOPIES_MAX) ncopies = NCOPIES_MAX;
    if (ncopies < 1) ncopies = 1;

    // atomics accumulate into ws -> must re-zero every launch (capture-safe)
    hipMemsetAsync(d_ws, 0, (size_t)ncopies * COPY_FLOATS * sizeof(float), stream);

    group_partial<<<GRID_BLOCKS, 512, 0, stream>>>(F, T, (float*)d_ws, nRows, ncopies);
    finalize<<<1, 256, 0, stream>>>((const float*)d_ws, ncopies, out);
}